// Round 5
// baseline (274.386 us; speedup 1.0000x reference)
//
#include <hip/hip_runtime.h>
#include <hip/hip_bf16.h>
#include <cmath>

typedef _Float16 h16x4 __attribute__((ext_vector_type(4)));
typedef _Float16 h16x8 __attribute__((ext_vector_type(8)));
typedef float    f32x4  __attribute__((ext_vector_type(4)));
typedef float    f32x16 __attribute__((ext_vector_type(16)));

#define CK 2304
#define KHALF 1152
#define PADH 1160          // val row pitch in halves (2320 B)
#define TP 32              // pixels per fused block

// ---- compile-time level tables ----
constexpr int  eH[4]   = {100, 50, 25, 13};
constexpr int  eW[4]   = {152, 76, 38, 19};
constexpr long eFTO[4] = {0, 7782400, 9728000, 10214400};
constexpr long eLOC[4] = {0, 30400, 38000, 39900};
constexpr long eSH[4]  = {40394, 101194, 116394, 120194};
constexpr long eREF[4] = {121182, 181982, 197182, 200982};
constexpr long eAD[4]  = {201970, 7984370, 9929970, 10416370};
constexpr float eSS[4] = {64.f, 128.f, 256.f, 512.f};

__device__ __constant__ int cHW[4]  = {15200, 3800, 950, 247};
__device__ __constant__ long cFTO2[4] = {0, 7782400, 9728000, 10214400};

static __device__ __forceinline__ h16x4 hsplat(float m) {
    _Float16 t = (_Float16)m;
    return (h16x4){t, t, t, t};
}

// ---------------- Kernel 0: weight prep (fp16) ----------------
__global__ void __launch_bounds__(256) wconv_kernel(
    const float* __restrict__ loc_w, const float* __restrict__ shape_w,
    const float* __restrict__ adw,
    _Float16* __restrict__ wbf2, _Float16* __restrict__ lsw)
{
    int i = blockIdx.x * 256 + threadIdx.x;
    if (i < 589824) {
        int kh = i / 294912;
        int r  = i - kh * 294912;
        int o  = r / 1152;
        int j  = r - o * 1152;
        int k  = j >> 7;
        int c  = kh * 128 + (j & 127);
        wbf2[i] = (_Float16)adw[o * CK + c * 9 + k];
    } else {
        int i2 = i - 589824;               // < 36864
        int o = i2 / CK;
        int j = i2 - o * CK;
        int k = j >> 8, c = j & 255;
        float v = 0.f;
        if (o == 0)      v = loc_w[c * 9 + k];
        else if (o == 1) v = shape_w[c * 9 + k];
        else if (o == 2) v = shape_w[CK + c * 9 + k];
        lsw[i2] = (_Float16)v;
    }
}

// ---------------- Kernel 1: NCHW fp32 -> NHWC fp16 transpose ----------------
__global__ void __launch_bounds__(256) transpose_kernel(
    const float* __restrict__ f0, const float* __restrict__ f1,
    const float* __restrict__ f2, const float* __restrict__ f3,
    _Float16* __restrict__ ft)
{
    __shared__ float lds[64][65];
    int bid = blockIdx.x, tid = threadIdx.x;
    int lvl = (bid < 1904) ? 0 : (bid < 2384) ? 1 : (bid < 2504) ? 2 : 3;
    int base = (lvl == 0) ? 0 : (lvl == 1) ? 1904 : (lvl == 2) ? 2384 : 2504;
    int nbhw = (lvl == 0) ? 238 : (lvl == 1) ? 60 : (lvl == 2) ? 15 : 4;
    const float* f = (lvl == 0) ? f0 : (lvl == 1) ? f1 : (lvl == 2) ? f2 : f3;
    int HW = cHW[lvl];
    int b = bid - base;
    int bh = b % nbhw;
    int cg = (b / nbhw) & 3;
    int n  = b / (nbhw * 4);
    int hw0 = bh * 64;

    int pxl = tid & 63, cl = tid >> 6;
    int hwr = hw0 + pxl;
    if (hwr < HW) {
        #pragma unroll
        for (int r = 0; r < 16; ++r) {
            int c = r * 4 + cl;
            lds[c][pxl] = f[(long)(n * 256 + cg * 64 + c) * HW + hwr];
        }
    }
    __syncthreads();
    int px2 = tid >> 2, q = tid & 3;
    int hww = hw0 + px2;
    if (hww < HW) {
        _Float16* dst = ft + cFTO2[lvl] + ((long)(n * HW + hww) << 8) + cg * 64 + q * 16;
        #pragma unroll
        for (int j = 0; j < 16; j += 4) {
            h16x4 v;
            v[0] = (_Float16)lds[q * 16 + j + 0][px2];
            v[1] = (_Float16)lds[q * 16 + j + 1][px2];
            v[2] = (_Float16)lds[q * 16 + j + 2][px2];
            v[3] = (_Float16)lds[q * 16 + j + 3][px2];
            *(h16x4*)(dst + j) = v;
        }
    }
}

// ---------------- fused body (templated per level) ----------------
template<int LVL>
static __device__ __forceinline__ void fused_body(
    int bidl,
    _Float16 (*val)[PADH], float* offsm, float (*shm)[2],
    int* pxh, int* pxw, int* pxn,
    const _Float16* __restrict__ ft,
    const float* __restrict__ offw,
    const _Float16* __restrict__ wbf2,
    const _Float16* __restrict__ lsw,
    const float* __restrict__ loc_b, const float* __restrict__ shape_b,
    float* __restrict__ out)
{
    constexpr int H = eH[LVL], W = eW[LVL];
    constexpr int HW = H * W;
    constexpr int total = 2 * HW;
    const _Float16* ftl = ft + eFTO[LVL];
    float* loc_o = out + eLOC[LVL];
    float* sh_o  = out + eSH[LVL];
    float* ref_o = out + eREF[LVL];
    float* ad_o  = out + eAD[LVL];

    int tid = threadIdx.x;
    int wv = tid >> 6, lane = tid & 63;
    int nn = lane & 15, c8 = lane >> 4;
    int pix0 = bidl * TP;

    // redB aliases dead val (phase B scratch, overwritten by phase C)
    float* redB = (float*)&val[0][0];      // [32][3][8]

    // ---- pre: pixel meta + offsets ----
    if (tid < TP) {
        int pix = pix0 + tid;
        if (pix < total) {
            int n = pix / HW;
            int rem = pix - n * HW;
            int hh = rem / W;
            pxn[tid] = n; pxh[tid] = hh; pxw[tid] = rem - hh * W;
        } else { pxn[tid] = -1; pxh[tid] = 0; pxw[tid] = 0; }
    }
    if (tid < 288) offsm[tid] = offw[tid];
    __syncthreads();

    // ---- Phase B: locshape GEMM, B-frags direct from global ft ----
    {
        int pxt = wv & 1, kq = wv >> 1;       // 2 px-tiles x 8 k-eighths
        int p = pxt * 16 + nn;
        int n = pxn[p], hh = pxh[p], ww = pxw[p];
        f32x4 acc = {0.f, 0.f, 0.f, 0.f};
        const _Float16* ar = lsw + nn * CK + kq * 288 + c8 * 8;
        #pragma unroll 3
        for (int s = 0; s < 9; ++s) {
            int j0 = kq * 288 + s * 32;
            int k = j0 >> 8;
            int c = (j0 & 255) + c8 * 8;
            int ky = (k * 171) >> 9;
            int kx = k - ky * 3;
            int y = hh - 1 + ky, x = ww - 1 + kx;
            h16x8 b = {0,0,0,0,0,0,0,0};
            if (n >= 0 && (unsigned)y < (unsigned)H && (unsigned)x < (unsigned)W)
                b = *(const h16x8*)(ftl + ((long)(n * HW + y * W + x) << 8) + c);
            h16x8 a = *(const h16x8*)(ar + s * 32);
            acc = __builtin_amdgcn_mfma_f32_16x16x32_f16(a, b, acc, 0, 0, 0);
        }
        if (c8 == 0) {
            #pragma unroll
            for (int r = 0; r < 3; ++r) redB[(p * 3 + r) * 8 + kq] = acc[r];
        }
    }
    __syncthreads();
    if (tid < 96) {
        int p = tid & 31, r = tid >> 5;
        float s = 0.f;
        #pragma unroll
        for (int kq = 0; kq < 8; ++kq) s += redB[(p * 3 + r) * 8 + kq];
        int pix = pix0 + p;
        if (pix < total) {
            int n = pxn[p];
            long sp = (long)pxh[p] * W + pxw[p];
            if (r == 0) {
                s += loc_b[0];
                loc_o[n * HW + sp] = 1.f / (1.f + expf(-s));
            } else {
                s += shape_b[r - 1];
                sh_o[(n * 2 + r - 1) * HW + sp] = s;
                ref_o[(n * 2 + r - 1) * HW + sp] = eSS[LVL] * expf(s);
                shm[p][r - 1] = s;
            }
        }
    }
    __syncthreads();

    // ---- Phases C/D per K-half ----
    int mt = wv >> 1, kg = wv & 1;
    int col = lane & 31, khalf = lane >> 5;
    f32x16 accT = {0,0,0,0,0,0,0,0,0,0,0,0,0,0,0,0};

    for (int kh = 0; kh < 2; ++kh) {
        // ---- Phase C: deformed bilinear im2col, half-K (128 ch) ----
        {
            int li = lane & 31;
            int sub = lane >> 5;
            int c4 = li * 4;
            int g = kh * 2 + (li >> 4);
            int choff = kh * 128 + c4;
            #pragma unroll 3
            for (int i = 0; i < 9; ++i) {
                int e = (i * 16 + wv) * 2 + sub;     // < 288
                int p = e / 9;
                int k = e - p * 9;
                int n = pxn[p];
                h16x4 r4 = {0, 0, 0, 0};
                if (n >= 0) {
                    float s0 = shm[p][0], s1 = shm[p][1];
                    int gk4 = (g * 9 + k) * 4;
                    float dy = offsm[gk4 + 0] * s0 + offsm[gk4 + 1] * s1;
                    float dx = offsm[gk4 + 2] * s0 + offsm[gk4 + 3] * s1;
                    int ky = (k * 171) >> 9;
                    int kx = k - ky * 3;
                    float py  = (float)(pxh[p] - 1 + ky) + dy;
                    float pxf = (float)(pxw[p] - 1 + kx) + dx;
                    float fy = floorf(py), fx = floorf(pxf);
                    float ly = py - fy, lx = pxf - fx;
                    int y0 = (int)fy, x0 = (int)fx;
                    int y1 = y0 + 1, x1 = x0 + 1;
                    float w00 = (1.f - ly) * (1.f - lx);
                    float w01 = (1.f - ly) * lx;
                    float w10 = ly * (1.f - lx);
                    float w11 = ly * lx;
                    bool by0 = (unsigned)y0 < (unsigned)H, by1 = (unsigned)y1 < (unsigned)H;
                    bool bx0 = (unsigned)x0 < (unsigned)W, bx1 = (unsigned)x1 < (unsigned)W;
                    float m00 = (by0 && bx0) ? w00 : 0.f;
                    float m01 = (by0 && bx1) ? w01 : 0.f;
                    float m10 = (by1 && bx0) ? w10 : 0.f;
                    float m11 = (by1 && bx1) ? w11 : 0.f;
                    int cy0 = min(max(y0, 0), H - 1), cy1 = min(max(y1, 0), H - 1);
                    int cx0 = min(max(x0, 0), W - 1), cx1 = min(max(x1, 0), W - 1);
                    const _Float16* fb = ftl + ((long)(n * HW) << 8) + choff;
                    h16x4 v00 = *(const h16x4*)(fb + ((long)(cy0 * W + cx0) << 8));
                    h16x4 v01 = *(const h16x4*)(fb + ((long)(cy0 * W + cx1) << 8));
                    h16x4 v10 = *(const h16x4*)(fb + ((long)(cy1 * W + cx0) << 8));
                    h16x4 v11 = *(const h16x4*)(fb + ((long)(cy1 * W + cx1) << 8));
                    r4 = v00 * hsplat(m00) + v01 * hsplat(m01)
                       + v10 * hsplat(m10) + v11 * hsplat(m11);
                }
                *(h16x4*)&val[p][k * 128 + c4] = r4;
            }
        }
        __syncthreads();

        // ---- Phase D: GEMM (32x32x16 f16), wave = oc-tile mt x K-group kg ----
        {
            const _Float16* wp = wbf2 + (long)kh * 294912
                               + (long)(mt * 32 + col) * KHALF + kg * 576 + khalf * 8;
            const _Float16* bp = &val[col][kg * 576 + khalf * 8];
            #pragma unroll 6
            for (int s = 0; s < 36; ++s) {
                h16x8 wf = *(const h16x8*)(wp + s * 16);
                h16x8 b0 = *(const h16x8*)(bp + s * 16);
                accT = __builtin_amdgcn_mfma_f32_32x32x16_f16(wf, b0, accT, 0, 0, 0);
            }
        }
        __syncthreads();
    }

    // ---- cross-kg reduce (part aliases dead val) + epilogue ----
    float* part = (float*)&val[0][0];
    if (kg == 1) {
        int tb = (mt * 64 + lane) * 18;
        #pragma unroll
        for (int q = 0; q < 16; q += 2)
            *(float2*)&part[tb + q] = make_float2(accT[q], accT[q + 1]);
    }
    __syncthreads();
    if (kg == 0) {
        int tb = (mt * 64 + lane) * 18;
        #pragma unroll
        for (int q = 0; q < 16; ++q) accT[q] += part[tb + q];
        int p = col;
        int n = pxn[p];
        if (n >= 0) {
            long sp = (long)pxh[p] * W + pxw[p];
            float* ob = ad_o + ((long)n * 256 + mt * 32) * HW + sp;
            #pragma unroll
            for (int reg = 0; reg < 16; ++reg) {
                int row = (reg & 3) + 8 * (reg >> 2) + 4 * khalf;
                float v = accT[reg];
                ob[(long)row * HW] = v > 0.f ? v : 0.f;
            }
        }
    }
}

__global__ void __launch_bounds__(1024, 8) fused_kernel(
    const _Float16* __restrict__ ft,
    const float* __restrict__ offw,
    const _Float16* __restrict__ wbf2,
    const _Float16* __restrict__ lsw,
    const float* __restrict__ loc_b, const float* __restrict__ shape_b,
    float* __restrict__ out)
{
    __shared__ _Float16 val[TP][PADH];     // 74,240 B
    __shared__ float offsm[288];
    __shared__ float shm[TP][2];
    __shared__ int pxh[TP], pxw[TP], pxn[TP];

    int bid = blockIdx.x;
    if (bid < 950)
        fused_body<0>(bid,       val, offsm, shm, pxh, pxw, pxn, ft, offw, wbf2, lsw, loc_b, shape_b, out);
    else if (bid < 1188)
        fused_body<1>(bid - 950, val, offsm, shm, pxh, pxw, pxn, ft, offw, wbf2, lsw, loc_b, shape_b, out);
    else if (bid < 1248)
        fused_body<2>(bid - 1188, val, offsm, shm, pxh, pxw, pxn, ft, offw, wbf2, lsw, loc_b, shape_b, out);
    else
        fused_body<3>(bid - 1248, val, offsm, shm, pxh, pxw, pxn, ft, offw, wbf2, lsw, loc_b, shape_b, out);
}

extern "C" void kernel_launch(void* const* d_in, const int* in_sizes, int n_in,
                              void* d_out, int out_size, void* d_ws, size_t ws_size,
                              hipStream_t stream)
{
    const float* f0 = (const float*)d_in[0];
    const float* f1 = (const float*)d_in[1];
    const float* f2 = (const float*)d_in[2];
    const float* f3 = (const float*)d_in[3];
    const float* loc_w    = (const float*)d_in[4];
    const float* loc_b    = (const float*)d_in[5];
    const float* shape_w  = (const float*)d_in[6];
    const float* shape_b  = (const float*)d_in[7];
    const float* offset_w = (const float*)d_in[8];
    const float* adapt_w  = (const float*)d_in[9];
    float* out = (float*)d_out;

    _Float16* wbf2 = (_Float16*)d_ws;          // 589,824 halves
    _Float16* lsw  = wbf2 + 589824;            // 36,864 halves
    _Float16* ft   = wbf2 + 626688;            // 10,340,864 halves

    wconv_kernel<<<2448, 256, 0, stream>>>(loc_w, shape_w, adapt_w, wbf2, lsw);
    transpose_kernel<<<2536, 256, 0, stream>>>(f0, f1, f2, f3, ft);
    fused_kernel<<<1264, 1024, 0, stream>>>(ft, offset_w, wbf2, lsw, loc_b, shape_b, out);
}

// Round 6
// 166.645 us; speedup vs baseline: 1.6465x; 1.6465x over previous
//
#include <hip/hip_runtime.h>
#include <hip/hip_bf16.h>
#include <cmath>

typedef _Float16 h16x4 __attribute__((ext_vector_type(4)));
typedef _Float16 h16x8 __attribute__((ext_vector_type(8)));
typedef float    f32x4  __attribute__((ext_vector_type(4)));
typedef float    f32x16 __attribute__((ext_vector_type(16)));

#define CK 2304
#define KHALF 1152
#define PADH 1160          // val row pitch in halves (2320 B)
#define TP 32              // pixels per fused block

// ---- compile-time level tables ----
constexpr int  eH[4]   = {100, 50, 25, 13};
constexpr int  eW[4]   = {152, 76, 38, 19};
constexpr long eFTO[4] = {0, 7782400, 9728000, 10214400};
constexpr long eLOC[4] = {0, 30400, 38000, 39900};
constexpr long eSH[4]  = {40394, 101194, 116394, 120194};
constexpr long eREF[4] = {121182, 181982, 197182, 200982};
constexpr long eAD[4]  = {201970, 7984370, 9929970, 10416370};
constexpr float eSS[4] = {64.f, 128.f, 256.f, 512.f};

__device__ __constant__ int cHW[4]  = {15200, 3800, 950, 247};
__device__ __constant__ long cFTO2[4] = {0, 7782400, 9728000, 10214400};

static __device__ __forceinline__ h16x4 hsplat(float m) {
    _Float16 t = (_Float16)m;
    return (h16x4){t, t, t, t};
}

// ---------------- Kernel 0: weight prep (fp16) ----------------
// wpack: MFMA-fragment-major: idx = ((((mt*2+kh)*2+kg)*36 + s)*64 + lane)*8 + u
//   -> oc = mt*32 + (lane&31); k = kh*1152 + kg*576 + (lane>>5)*8 + s*16 + u
// lsw [16][2304], j = k*256 + c ; rows 0..2 = loc_w, shape_w0, shape_w1
__global__ void __launch_bounds__(256) wconv_kernel(
    const float* __restrict__ loc_w, const float* __restrict__ shape_w,
    const float* __restrict__ adw,
    _Float16* __restrict__ wpack, _Float16* __restrict__ lsw)
{
    int i = blockIdx.x * 256 + threadIdx.x;
    if (i < 589824) {
        int u    = i & 7;
        int lane = (i >> 3) & 63;
        int t    = i >> 9;          // (((mt*2+kh)*2+kg)*36 + s)
        int s    = t % 36;
        int q    = t / 36;          // (mt*2+kh)*2+kg
        int kg   = q & 1;
        int kh   = (q >> 1) & 1;
        int mt   = q >> 2;
        int oc = mt * 32 + (lane & 31);
        int k  = kh * KHALF + kg * 576 + (lane >> 5) * 8 + s * 16 + u;
        int kk = k >> 8, c = k & 255;
        wpack[i] = (_Float16)adw[oc * CK + c * 9 + kk];
    } else {
        int i2 = i - 589824;               // < 36864
        int o = i2 / CK;
        int j = i2 - o * CK;
        int k = j >> 8, c = j & 255;
        float v = 0.f;
        if (o == 0)      v = loc_w[c * 9 + k];
        else if (o == 1) v = shape_w[c * 9 + k];
        else if (o == 2) v = shape_w[CK + c * 9 + k];
        lsw[i2] = (_Float16)v;
    }
}

// ---------------- Kernel 1: NCHW fp32 -> NHWC fp16 transpose ----------------
__global__ void __launch_bounds__(256) transpose_kernel(
    const float* __restrict__ f0, const float* __restrict__ f1,
    const float* __restrict__ f2, const float* __restrict__ f3,
    _Float16* __restrict__ ft)
{
    __shared__ float lds[64][65];
    int bid = blockIdx.x, tid = threadIdx.x;
    int lvl = (bid < 1904) ? 0 : (bid < 2384) ? 1 : (bid < 2504) ? 2 : 3;
    int base = (lvl == 0) ? 0 : (lvl == 1) ? 1904 : (lvl == 2) ? 2384 : 2504;
    int nbhw = (lvl == 0) ? 238 : (lvl == 1) ? 60 : (lvl == 2) ? 15 : 4;
    const float* f = (lvl == 0) ? f0 : (lvl == 1) ? f1 : (lvl == 2) ? f2 : f3;
    int HW = cHW[lvl];
    int b = bid - base;
    int bh = b % nbhw;
    int cg = (b / nbhw) & 3;
    int n  = b / (nbhw * 4);
    int hw0 = bh * 64;

    int pxl = tid & 63, cl = tid >> 6;
    int hwr = hw0 + pxl;
    if (hwr < HW) {
        #pragma unroll
        for (int r = 0; r < 16; ++r) {
            int c = r * 4 + cl;
            lds[c][pxl] = f[(long)(n * 256 + cg * 64 + c) * HW + hwr];
        }
    }
    __syncthreads();
    int px2 = tid >> 2, q = tid & 3;
    int hww = hw0 + px2;
    if (hww < HW) {
        _Float16* dst = ft + cFTO2[lvl] + ((long)(n * HW + hww) << 8) + cg * 64 + q * 16;
        #pragma unroll
        for (int j = 0; j < 16; j += 4) {
            h16x4 v;
            v[0] = (_Float16)lds[q * 16 + j + 0][px2];
            v[1] = (_Float16)lds[q * 16 + j + 1][px2];
            v[2] = (_Float16)lds[q * 16 + j + 2][px2];
            v[3] = (_Float16)lds[q * 16 + j + 3][px2];
            *(h16x4*)(dst + j) = v;
        }
    }
}

// ---------------- fused body (templated per level) ----------------
template<int LVL>
static __device__ __forceinline__ void fused_body(
    int bidl,
    _Float16 (*val)[PADH], float* offsm, float (*shm)[2],
    int* pxh, int* pxw, int* pxn,
    const _Float16* __restrict__ ft,
    const float* __restrict__ offw,
    const _Float16* __restrict__ wpack,
    const _Float16* __restrict__ lsw,
    const float* __restrict__ loc_b, const float* __restrict__ shape_b,
    float* __restrict__ out)
{
    constexpr int H = eH[LVL], W = eW[LVL];
    constexpr int HW = H * W;
    constexpr int total = 2 * HW;
    const _Float16* ftl = ft + eFTO[LVL];
    float* loc_o = out + eLOC[LVL];
    float* sh_o  = out + eSH[LVL];
    float* ref_o = out + eREF[LVL];
    float* ad_o  = out + eAD[LVL];

    int tid = threadIdx.x;
    int wv = tid >> 6, lane = tid & 63;
    int nn = lane & 15, c8 = lane >> 4;
    int pix0 = bidl * TP;

    // redB aliases dead val (phase B scratch, overwritten by phase C)
    float* redB = (float*)&val[0][0];      // [32][3][8]

    // ---- pre: pixel meta + offsets ----
    if (tid < TP) {
        int pix = pix0 + tid;
        if (pix < total) {
            int n = pix / HW;
            int rem = pix - n * HW;
            int hh = rem / W;
            pxn[tid] = n; pxh[tid] = hh; pxw[tid] = rem - hh * W;
        } else { pxn[tid] = -1; pxh[tid] = 0; pxw[tid] = 0; }
    }
    if (tid < 288) offsm[tid] = offw[tid];
    __syncthreads();

    // ---- Phase B: locshape GEMM, B-frags direct from global ft ----
    {
        int pxt = wv & 1, kq = wv >> 1;       // 2 px-tiles x 8 k-eighths
        int p = pxt * 16 + nn;
        int n = pxn[p], hh = pxh[p], ww = pxw[p];
        f32x4 acc = {0.f, 0.f, 0.f, 0.f};
        const _Float16* ar = lsw + nn * CK + kq * 288 + c8 * 8;
        #pragma unroll 3
        for (int s = 0; s < 9; ++s) {
            int j0 = kq * 288 + s * 32;
            int k = j0 >> 8;
            int c = (j0 & 255) + c8 * 8;
            int ky = (k * 171) >> 9;
            int kx = k - ky * 3;
            int y = hh - 1 + ky, x = ww - 1 + kx;
            h16x8 b = {0,0,0,0,0,0,0,0};
            if (n >= 0 && (unsigned)y < (unsigned)H && (unsigned)x < (unsigned)W)
                b = *(const h16x8*)(ftl + ((long)(n * HW + y * W + x) << 8) + c);
            h16x8 a = *(const h16x8*)(ar + s * 32);
            acc = __builtin_amdgcn_mfma_f32_16x16x32_f16(a, b, acc, 0, 0, 0);
        }
        if (c8 == 0) {
            #pragma unroll
            for (int r = 0; r < 3; ++r) redB[(p * 3 + r) * 8 + kq] = acc[r];
        }
    }
    __syncthreads();
    if (tid < 96) {
        int p = tid & 31, r = tid >> 5;
        float s = 0.f;
        #pragma unroll
        for (int kq = 0; kq < 8; ++kq) s += redB[(p * 3 + r) * 8 + kq];
        int pix = pix0 + p;
        if (pix < total) {
            int n = pxn[p];
            long sp = (long)pxh[p] * W + pxw[p];
            if (r == 0) {
                s += loc_b[0];
                loc_o[n * HW + sp] = 1.f / (1.f + expf(-s));
            } else {
                s += shape_b[r - 1];
                sh_o[(n * 2 + r - 1) * HW + sp] = s;
                ref_o[(n * 2 + r - 1) * HW + sp] = eSS[LVL] * expf(s);
                shm[p][r - 1] = s;
            }
        }
    }
    __syncthreads();

    // ---- Phases C/D per K-half ----
    int mt = wv >> 1, kg = wv & 1;
    int col = lane & 31, khalf = lane >> 5;
    f32x16 accT = {0,0,0,0,0,0,0,0,0,0,0,0,0,0,0,0};

    for (int kh = 0; kh < 2; ++kh) {
        // ---- Phase C: deformed bilinear im2col, half-K (128 ch) ----
        {
            int li = lane & 31;
            int sub = lane >> 5;
            int c4 = li * 4;
            int g = kh * 2 + (li >> 4);
            int choff = kh * 128 + c4;
            #pragma unroll 3
            for (int i = 0; i < 9; ++i) {
                int e = (i * 16 + wv) * 2 + sub;     // < 288
                int p = e / 9;
                int k = e - p * 9;
                int n = pxn[p];
                h16x4 r4 = {0, 0, 0, 0};
                if (n >= 0) {
                    float s0 = shm[p][0], s1 = shm[p][1];
                    int gk4 = (g * 9 + k) * 4;
                    float dy = offsm[gk4 + 0] * s0 + offsm[gk4 + 1] * s1;
                    float dx = offsm[gk4 + 2] * s0 + offsm[gk4 + 3] * s1;
                    int ky = (k * 171) >> 9;
                    int kx = k - ky * 3;
                    float py  = (float)(pxh[p] - 1 + ky) + dy;
                    float pxf = (float)(pxw[p] - 1 + kx) + dx;
                    float fy = floorf(py), fx = floorf(pxf);
                    float ly = py - fy, lx = pxf - fx;
                    int y0 = (int)fy, x0 = (int)fx;
                    int y1 = y0 + 1, x1 = x0 + 1;
                    float w00 = (1.f - ly) * (1.f - lx);
                    float w01 = (1.f - ly) * lx;
                    float w10 = ly * (1.f - lx);
                    float w11 = ly * lx;
                    bool by0 = (unsigned)y0 < (unsigned)H, by1 = (unsigned)y1 < (unsigned)H;
                    bool bx0 = (unsigned)x0 < (unsigned)W, bx1 = (unsigned)x1 < (unsigned)W;
                    float m00 = (by0 && bx0) ? w00 : 0.f;
                    float m01 = (by0 && bx1) ? w01 : 0.f;
                    float m10 = (by1 && bx0) ? w10 : 0.f;
                    float m11 = (by1 && bx1) ? w11 : 0.f;
                    int cy0 = min(max(y0, 0), H - 1), cy1 = min(max(y1, 0), H - 1);
                    int cx0 = min(max(x0, 0), W - 1), cx1 = min(max(x1, 0), W - 1);
                    const _Float16* fb = ftl + ((long)(n * HW) << 8) + choff;
                    h16x4 v00 = *(const h16x4*)(fb + ((long)(cy0 * W + cx0) << 8));
                    h16x4 v01 = *(const h16x4*)(fb + ((long)(cy0 * W + cx1) << 8));
                    h16x4 v10 = *(const h16x4*)(fb + ((long)(cy1 * W + cx0) << 8));
                    h16x4 v11 = *(const h16x4*)(fb + ((long)(cy1 * W + cx1) << 8));
                    r4 = v00 * hsplat(m00) + v01 * hsplat(m01)
                       + v10 * hsplat(m10) + v11 * hsplat(m11);
                }
                *(h16x4*)&val[p][k * 128 + c4] = r4;
            }
        }
        __syncthreads();

        // ---- Phase D: GEMM (32x32x16 f16); A-frags fragment-packed, coalesced ----
        {
            const _Float16* wp = wpack
                + ((long)(((mt * 2 + kh) * 2 + kg) * 36) * 64 + lane) * 8;
            const _Float16* bp = &val[col][kg * 576 + khalf * 8];
            #pragma unroll 4
            for (int s = 0; s < 36; ++s) {
                h16x8 wf = *(const h16x8*)(wp + s * 512);
                h16x8 b0 = *(const h16x8*)(bp + s * 16);
                accT = __builtin_amdgcn_mfma_f32_32x32x16_f16(wf, b0, accT, 0, 0, 0);
            }
        }
        __syncthreads();
    }

    // ---- cross-kg reduce (part aliases dead val) + epilogue ----
    float* part = (float*)&val[0][0];
    if (kg == 1) {
        int tb = (mt * 64 + lane) * 18;
        #pragma unroll
        for (int q = 0; q < 16; q += 2)
            *(float2*)&part[tb + q] = make_float2(accT[q], accT[q + 1]);
    }
    __syncthreads();
    if (kg == 0) {
        int tb = (mt * 64 + lane) * 18;
        #pragma unroll
        for (int q = 0; q < 16; ++q) accT[q] += part[tb + q];
        int p = col;
        int n = pxn[p];
        if (n >= 0) {
            long sp = (long)pxh[p] * W + pxw[p];
            float* ob = ad_o + ((long)n * 256 + mt * 32) * HW + sp;
            #pragma unroll
            for (int reg = 0; reg < 16; ++reg) {
                int row = (reg & 3) + 8 * (reg >> 2) + 4 * khalf;
                float v = accT[reg];
                ob[(long)row * HW] = v > 0.f ? v : 0.f;
            }
        }
    }
}

__global__ void __launch_bounds__(1024, 8) fused_kernel(
    const _Float16* __restrict__ ft,
    const float* __restrict__ offw,
    const _Float16* __restrict__ wpack,
    const _Float16* __restrict__ lsw,
    const float* __restrict__ loc_b, const float* __restrict__ shape_b,
    float* __restrict__ out)
{
    __shared__ _Float16 val[TP][PADH];     // 74,240 B
    __shared__ float offsm[288];
    __shared__ float shm[TP][2];
    __shared__ int pxh[TP], pxw[TP], pxn[TP];

    int bid = blockIdx.x;
    if (bid < 950)
        fused_body<0>(bid,       val, offsm, shm, pxh, pxw, pxn, ft, offw, wpack, lsw, loc_b, shape_b, out);
    else if (bid < 1188)
        fused_body<1>(bid - 950, val, offsm, shm, pxh, pxw, pxn, ft, offw, wpack, lsw, loc_b, shape_b, out);
    else if (bid < 1248)
        fused_body<2>(bid - 1188, val, offsm, shm, pxh, pxw, pxn, ft, offw, wpack, lsw, loc_b, shape_b, out);
    else
        fused_body<3>(bid - 1248, val, offsm, shm, pxh, pxw, pxn, ft, offw, wpack, lsw, loc_b, shape_b, out);
}

extern "C" void kernel_launch(void* const* d_in, const int* in_sizes, int n_in,
                              void* d_out, int out_size, void* d_ws, size_t ws_size,
                              hipStream_t stream)
{
    const float* f0 = (const float*)d_in[0];
    const float* f1 = (const float*)d_in[1];
    const float* f2 = (const float*)d_in[2];
    const float* f3 = (const float*)d_in[3];
    const float* loc_w    = (const float*)d_in[4];
    const float* loc_b    = (const float*)d_in[5];
    const float* shape_w  = (const float*)d_in[6];
    const float* shape_b  = (const float*)d_in[7];
    const float* offset_w = (const float*)d_in[8];
    const float* adapt_w  = (const float*)d_in[9];
    float* out = (float*)d_out;

    _Float16* wpack = (_Float16*)d_ws;         // 589,824 halves (frag-packed)
    _Float16* lsw   = wpack + 589824;          // 36,864 halves
    _Float16* ft    = wpack + 626688;          // 10,340,864 halves

    wconv_kernel<<<2448, 256, 0, stream>>>(loc_w, shape_w, adapt_w, wpack, lsw);
    transpose_kernel<<<2536, 256, 0, stream>>>(f0, f1, f2, f3, ft);
    fused_kernel<<<1264, 1024, 0, stream>>>(ft, offset_w, wpack, lsw, loc_b, shape_b, out);
}